// Round 1
// baseline (329.453 us; speedup 1.0000x reference)
//
#include <hip/hip_runtime.h>
#include <hip/hip_fp16.h>

#define A     96
#define DET0  256
#define NZ    32
#define NY    256
#define NX    256
#define T     256
#define TLEN  32
#define NCH   8
#define LAMB  0.01f

// ws layout (floats):
//   trig  : [A][2]            @ 0       (192, padded to 256; padding also absorbs
//                                        the harmless -128B tap read in k_backward)
//   res_t : [A][DET0][NZ]     @ 256     (786,432) fp32, seeded -p, atomic +=
//   vol_h : [NY][NX][NZ] f16  @ 786,688 (2,097,152 ushorts)
#define TRIG_OFF  0
#define REST_OFF  256
#define VOLB_OFF  786688

// accumulate 2 f16 (packed in a dword) * w into acc[0..1] — compiler forms
// v_fma_mix_f32 (f32 fma with f16 src selected by op_sel), no unpack ops.
__device__ __forceinline__ void accp(float* acc, unsigned v, float w) {
    __half2 h = *reinterpret_cast<__half2*>(&v);
    acc[0] = fmaf(w, __low2float(h),  acc[0]);
    acc[1] = fmaf(w, __high2float(h), acc[1]);
}
__device__ __forceinline__ void acc8h(float* acc, uint4 q, float w) {
    accp(acc + 0, q.x, w);
    accp(acc + 2, q.y, w);
    accp(acc + 4, q.z, w);
    accp(acc + 6, q.w, w);
}

// ---------------------------------------------------------------------------
// K1: transpose vol (z,y,x) fp32 -> vol_h (y,x,z) f16; fill trig table;
//     seed res_t = -p_perm (blocks with y < A double as (u-chunk, angle) seeders).
// grid (NX/64, NY), block 256
__global__ __launch_bounds__(256) void k_transpose(const float* __restrict__ src,
                                                   unsigned short* __restrict__ vol_h,
                                                   float* __restrict__ trig,
                                                   const float* __restrict__ p,
                                                   float* __restrict__ res_t) {
    __shared__ float lds[64 * 33];   // 2112 floats; seed phase reuses 32x65 <= 2078
    const int y   = blockIdx.y;
    const int x0  = blockIdx.x * 64;
    const int tid = threadIdx.x;

    if (blockIdx.x == 0 && y == 0 && tid < A) {
        float th = (float)tid * (float)(3.14159265358979323846 / (double)A);
        trig[2 * tid]     = cosf(th);
        trig[2 * tid + 1] = sinf(th);
    }

    const int xr = tid & 63;
    const int zr = tid >> 6;  // 0..3
    #pragma unroll
    for (int pz = 0; pz < 8; ++pz) {
        int z = pz * 4 + zr;
        lds[xr * 33 + z] = src[(z * NY + y) * NX + x0 + xr];
    }
    __syncthreads();
    const int zw = tid & 31;
    const int xw = tid >> 5;  // 0..7
    #pragma unroll
    for (int px = 0; px < 8; ++px) {
        int xi = px * 8 + xw;
        vol_h[(y * NX + x0 + xi) * NZ + zw] =
            __half_as_ushort(__float2half(lds[xi * 33 + zw]));
    }

    // ---- seed res_t[a][u][z] = -p[a][perm(z)][u] for a = y, u-chunk = blockIdx.x
    if (y < A) {
        const int a  = y;
        const int u0 = blockIdx.x * 64;
        __syncthreads();                      // transpose reads of lds are done
        const int col = tid & 63;
        const int r0  = tid >> 6;
        #pragma unroll
        for (int i = 0; i < 8; ++i) {
            int r = i * 4 + r0;
            lds[r * 65 + col] = p[a * 8192 + r * 256 + u0 + col];
        }
        __syncthreads();
        const int ul = tid >> 2;
        const int zb = (tid & 3) * 8;
        float o[8];
        #pragma unroll
        for (int k = 0; k < 8; ++k) {
            int z = zb + k;
            int r = ((z & 7) << 2) + (z >> 3);
            o[k] = -lds[r * 65 + ul];
        }
        float4* d = (float4*)(res_t + (a * DET0 + u0 + ul) * NZ + zb);
        d[0] = make_float4(o[0], o[1], o[2], o[3]);
        d[1] = make_float4(o[4], o[5], o[6], o[7]);
    }
}

// ---------------------------------------------------------------------------
// t-range helper: solve L <= t*g + b <= H for t (tt = t - 127.5 domain)
__device__ __forceinline__ void rng(float g, float b, float L, float H,
                                    float& lo, float& hi) {
    if (fabsf(g) > 1e-5f) {
        float r0 = (L - b) / g, r1 = (H - b) / g;
        lo = fminf(r0, r1); hi = fmaxf(r0, r1);
    } else {
        bool in = (b >= L && b <= H);
        lo = in ? -1e9f : 1e9f;
        hi = in ? 1e9f : -1e9f;
    }
}
__device__ __forceinline__ int clampi(float v) {
    return (int)fminf(fmaxf(v, -2.f), 258.f);
}

// fully-masked edge sample (boundary t's)
__device__ __forceinline__ void sample_edge(const char* base, float ix, float iy,
                                            float* acc) {
    float xf = floorf(ix), yf = floorf(iy);
    float fx = ix - xf, fy = iy - yf;
    int x0 = (int)xf, y0 = (int)yf;
    float wx0 = 1.f - fx, wx1 = fx, wy0 = 1.f - fy, wy1 = fy;
    if ((unsigned)x0 >= NX)       wx0 = 0.f;
    if ((unsigned)(x0 + 1) >= NX) wx1 = 0.f;
    if ((unsigned)y0 >= NY)       wy0 = 0.f;
    if ((unsigned)(y0 + 1) >= NY) wy1 = 0.f;
    if ((wx0 == 0.f && wx1 == 0.f) || (wy0 == 0.f && wy1 == 0.f)) return;
    int cx0 = min(max(x0, 0), NX - 1);
    int cx1 = min(max(x0 + 1, 0), NX - 1);
    int cy0 = min(max(y0, 0), NY - 1);
    int cy1 = min(max(y0 + 1, 0), NY - 1);
    uint4 q00 = *(const uint4*)(base + ((size_t)((cy0 << 8) + cx0) << 6));
    uint4 q01 = *(const uint4*)(base + ((size_t)((cy0 << 8) + cx1) << 6));
    uint4 q10 = *(const uint4*)(base + ((size_t)((cy1 << 8) + cx0) << 6));
    uint4 q11 = *(const uint4*)(base + ((size_t)((cy1 << 8) + cx1) << 6));
    acc8h(acc, q00, wy0 * wx0);
    acc8h(acc, q01, wy0 * wx1);
    acc8h(acc, q10, wy1 * wx0);
    acc8h(acc, q11, wy1 * wx1);
}

// ---------------------------------------------------------------------------
// K2: forward projection. thread = (u, z-quarter of 8), no LDS.
// Accumulates directly into res_t with fire-and-forget f32 atomics
// (seeded -p by K1), eliminating the part buffer + combine kernel.
// grid (4 u-groups, NCH t-chunks, A), block 256
__global__ __launch_bounds__(256) void k_forward(const unsigned short* __restrict__ vol_h,
                                                 const float* __restrict__ trig,
                                                 float* __restrict__ res_t) {
    const int tid = threadIdx.x;
    const int a  = blockIdx.z;
    const int u  = blockIdx.x * 64 + (tid >> 2);
    const int zq = tid & 3;                 // 8 z per lane
    const int t0 = blockIdx.y * TLEN;

    const float c = trig[2 * a];
    const float s = trig[2 * a + 1];
    const float uu = (float)u - 127.5f;
    const float bx = fmaf(-uu, s, 127.5f);  // ix = tt*c + bx
    const float by = fmaf(uu, c, 127.5f);   // iy = tt*s + by

    // full valid range (contribution possibly nonzero): ix,iy in [-1, 256]
    float lo1, hi1, lo2, hi2;
    rng(c, bx, -1.f, 256.f, lo1, hi1);
    rng(s, by, -1.f, 256.f, lo2, hi2);
    float fl = fmaxf(lo1, lo2), fh = fminf(hi1, hi2);
    int tF0 = max(t0, clampi(ceilf(fl + 127.5f)));
    int tF1 = min(t0 + TLEN - 1, clampi(floorf(fh + 127.5f)));
    if (tF1 < tF0) return;                  // empty chunk: no atomics, exit
    // strict interior (no clamping/masking needed): ix,iy in [1, 253.5], shrink 1
    rng(c, bx, 1.f, 253.5f, lo1, hi1);
    rng(s, by, 1.f, 253.5f, lo2, hi2);
    float il = fmaxf(lo1, lo2), ih = fminf(hi1, hi2);
    int tI0 = max(clampi(ceilf(il + 127.5f)) + 1, tF0);
    int tI1 = min(clampi(floorf(ih + 127.5f)) - 1, tF1);
    if (tI0 > tI1) { tI0 = tF1 + 1; tI1 = tF1; }

    const char* base = (const char*)vol_h + zq * 16;
    float acc[8];
    #pragma unroll
    for (int k = 0; k < 8; ++k) acc[k] = 0.f;

    for (int t = tF0; t < tI0; ++t) {
        float ttf = (float)t - 127.5f;
        sample_edge(base, fmaf(ttf, c, bx), fmaf(ttf, s, by), acc);
    }
    #pragma unroll 2
    for (int t = tI0; t <= tI1; ++t) {
        float ttf = (float)t - 127.5f;
        float ix = fmaf(ttf, c, bx);
        float iy = fmaf(ttf, s, by);
        float xf = floorf(ix), yf = floorf(iy);
        float fx = ix - xf, fy = iy - yf;
        int row = ((int)yf << 8) + (int)xf;
        const char* p0 = base + ((size_t)row << 6);
        uint4 q00 = *(const uint4*)(p0);
        uint4 q01 = *(const uint4*)(p0 + 64);
        uint4 q10 = *(const uint4*)(p0 + 16384);
        uint4 q11 = *(const uint4*)(p0 + 16384 + 64);
        float wx0 = 1.f - fx, wy0 = 1.f - fy;
        acc8h(acc, q00, wy0 * wx0);
        acc8h(acc, q01, wy0 * fx);
        acc8h(acc, q10, fy * wx0);
        acc8h(acc, q11, fy * fx);
    }
    for (int t = tI1 + 1; t <= tF1; ++t) {
        float ttf = (float)t - 127.5f;
        sample_edge(base, fmaf(ttf, c, bx), fmaf(ttf, s, by), acc);
    }

    float* dst = res_t + ((a * DET0 + u) * NZ + zq * 8);
    #pragma unroll
    for (int k = 0; k < 8; ++k) unsafeAtomicAdd(dst + k, acc[k]);
}

// ---------------------------------------------------------------------------
// K3: backprojection, thread = (x, z-quarter of 4). Weights in LDS per (a,x);
// output re-transposed through LDS for coalesced stores.
// LDS 41,088 B (float2 w + int off + ob) -> 3 blocks/CU (was 53,376 B -> 2).
// The two taps are always 128 B apart; zero-weight clamped taps may read the
// trig-padding/neighbor rows harmlessly (x0 of the -128B underflow stays in ws).
// grid (NX/32, NY), block 256
__global__ __launch_bounds__(256) void k_backward(const float* __restrict__ res_t,
                                                  const float* __restrict__ trig,
                                                  float* __restrict__ out) {
    __shared__ float2 wbw[A * 32];  // 24,576 B: w0, w1
    __shared__ int    wbo[A * 32];  // 12,288 B: byte offset of tap0 (= tap1 - 128)
    __shared__ float  ob[32 * 33];  //  4,224 B output staging
    const int tid = threadIdx.x;
    const int y  = blockIdx.y;
    const int xb = blockIdx.x * 32;

    for (int e = tid; e < A * 32; e += 256) {
        int a  = e >> 5;
        int xs = e & 31;
        float cc = trig[2 * a];
        float ss = trig[2 * a + 1];
        float xx = (float)(xb + xs) - 127.5f;
        float yy = (float)y - 127.5f;
        float ub = fmaf(-xx, ss, fmaf(yy, cc, 127.5f));
        float uf = floorf(ub);
        float fu = ub - uf;
        int i0 = (int)uf;
        float w0 = ((unsigned)i0 < DET0) ? (1.f - fu) : 0.f;
        float w1 = ((unsigned)(i0 + 1) < DET0) ? fu : 0.f;
        int c1 = min(max(i0 + 1, 0), DET0);       // 0..256; tap0 row = c1-1
        wbw[e] = make_float2(w0, w1);
        wbo[e] = ((a * DET0 + c1) * NZ - NZ) << 2;
    }
    __syncthreads();

    const int xs = tid >> 3;
    const int zq = tid & 7;          // 4 z per lane
    const char* rbase = (const char*)res_t + zq * 16;
    float4 acc = make_float4(0.f, 0.f, 0.f, 0.f);
    #pragma unroll 4
    for (int a = 0; a < A; ++a) {
        float2 w  = wbw[a * 32 + xs];
        int   off = wbo[a * 32 + xs];
        float4 v0 = *(const float4*)(rbase + off);
        float4 v1 = *(const float4*)(rbase + off + 128);
        acc.x = fmaf(w.x, v0.x, fmaf(w.y, v1.x, acc.x));
        acc.y = fmaf(w.x, v0.y, fmaf(w.y, v1.y, acc.y));
        acc.z = fmaf(w.x, v0.z, fmaf(w.y, v1.z, acc.z));
        acc.w = fmaf(w.x, v0.w, fmaf(w.y, v1.w, acc.w));
    }

    ob[(zq * 4 + 0) * 33 + xs] = acc.x;
    ob[(zq * 4 + 1) * 33 + xs] = acc.y;
    ob[(zq * 4 + 2) * 33 + xs] = acc.z;
    ob[(zq * 4 + 3) * 33 + xs] = acc.w;
    __syncthreads();

    const int z  = tid >> 3;
    const int x4 = (tid & 7) * 4;
    float4 o = make_float4(ob[z * 33 + x4],     ob[z * 33 + x4 + 1],
                           ob[z * 33 + x4 + 2], ob[z * 33 + x4 + 3]);
    float4* dst = (float4*)(out + (size_t)z * (NY * NX) + y * NX + xb + x4);
    *dst = make_float4(-LAMB * o.x, -LAMB * o.y, -LAMB * o.z, -LAMB * o.w);
}

// ---------------------------------------------------------------------------
extern "C" void kernel_launch(void* const* d_in, const int* in_sizes, int n_in,
                              void* d_out, int out_size, void* d_ws, size_t ws_size,
                              hipStream_t stream) {
    const float* x = (const float*)d_in[0];   // (1,1,32,256,256)
    const float* p = (const float*)d_in[1];   // (1,1,384,8,256)
    float* out = (float*)d_out;               // (1,1,32,256,256)
    float* ws  = (float*)d_ws;

    float*          trig  = ws + TRIG_OFF;
    float*          res_t = ws + REST_OFF;
    unsigned short* vol_h = (unsigned short*)(ws + VOLB_OFF);

    k_transpose<<<dim3(NX / 64, NY), 256, 0, stream>>>(x, vol_h, trig, p, res_t);
    k_forward  <<<dim3(4, NCH, A), 256, 0, stream>>>(vol_h, trig, res_t);
    k_backward <<<dim3(NX / 32, NY), 256, 0, stream>>>(res_t, trig, out);
}

// Round 3
// 195.162 us; speedup vs baseline: 1.6881x; 1.6881x over previous
//
#include <hip/hip_runtime.h>
#include <hip/hip_fp16.h>

#define A     96
#define DET0  256
#define NZ    32
#define NY    256
#define NX    256
#define T     256
#define LAMB  0.01f

// ws layout (floats):
//   trig  : [A][2]            @ 0        (192, padded to 256; padding absorbs the
//                                         harmless -128B zero-weight tap in k_backward)
//   res_t : [A][DET0][NZ]     @ 256      (786,432) fp32, seeded -p_perm by k_transpose
//   vol_h : [NY][NX][NZ] f16  @ 786,688  (2,097,152 ushorts = 1,048,576 floats)
//   part  : [C][A][DET0][NZ]  @ 1,835,264
#define TRIG_OFF  0
#define REST_OFF  256
#define VOLB_OFF  786688
#define PART_OFF  1835264
#define RES_ELEMS 786432

// accumulate 2 f16 (packed in a dword) * w into acc[0..1] — fpext+fma is the
// canonical pattern for v_fma_mix_f32 (f32 fma reading f16 src half), no unpack.
__device__ __forceinline__ void accp(float* acc, unsigned v, float w) {
    __half2 h = *reinterpret_cast<__half2*>(&v);
    acc[0] = fmaf(w, __low2float(h),  acc[0]);
    acc[1] = fmaf(w, __high2float(h), acc[1]);
}
__device__ __forceinline__ void acc8h(float* acc, uint4 q, float w) {
    accp(acc + 0, q.x, w);
    accp(acc + 2, q.y, w);
    accp(acc + 4, q.z, w);
    accp(acc + 6, q.w, w);
}

// ---------------------------------------------------------------------------
// K1: transpose vol (z,y,x) fp32 -> vol_h (y,x,z) f16; fill trig table;
//     seed res_t = -p_perm (blocks with y < A double as (u-chunk, angle) seeders).
// grid (NX/64, NY), block 256
__global__ __launch_bounds__(256) void k_transpose(const float* __restrict__ src,
                                                   unsigned short* __restrict__ vol_h,
                                                   float* __restrict__ trig,
                                                   const float* __restrict__ p,
                                                   float* __restrict__ res_t) {
    __shared__ float lds[64 * 33];   // 2112 floats; seed phase reuses 32x65 <= 2078
    const int y   = blockIdx.y;
    const int x0  = blockIdx.x * 64;
    const int tid = threadIdx.x;

    if (blockIdx.x == 0 && y == 0 && tid < A) {
        float th = (float)tid * (float)(3.14159265358979323846 / (double)A);
        trig[2 * tid]     = cosf(th);
        trig[2 * tid + 1] = sinf(th);
    }

    const int xr = tid & 63;
    const int zr = tid >> 6;  // 0..3
    #pragma unroll
    for (int pz = 0; pz < 8; ++pz) {
        int z = pz * 4 + zr;
        lds[xr * 33 + z] = src[(z * NY + y) * NX + x0 + xr];
    }
    __syncthreads();
    const int zw = tid & 31;
    const int xw = tid >> 5;  // 0..7
    #pragma unroll
    for (int px = 0; px < 8; ++px) {
        int xi = px * 8 + xw;
        vol_h[(y * NX + x0 + xi) * NZ + zw] =
            __half_as_ushort(__float2half(lds[xi * 33 + zw]));
    }

    // ---- seed res_t[a][u][z] = -p[a][perm(z)][u] for a = y, u-chunk = blockIdx.x
    if (y < A) {
        const int a  = y;
        const int u0 = blockIdx.x * 64;
        __syncthreads();                      // transpose reads of lds are done
        const int col = tid & 63;
        const int r0  = tid >> 6;
        #pragma unroll
        for (int i = 0; i < 8; ++i) {
            int r = i * 4 + r0;
            lds[r * 65 + col] = p[a * 8192 + r * 256 + u0 + col];
        }
        __syncthreads();
        const int ul = tid >> 2;
        const int zb = (tid & 3) * 8;
        float o[8];
        #pragma unroll
        for (int k = 0; k < 8; ++k) {
            int z = zb + k;
            int r = ((z & 7) << 2) + (z >> 3);
            o[k] = -lds[r * 65 + ul];
        }
        float4* d = (float4*)(res_t + (a * DET0 + u0 + ul) * NZ + zb);
        d[0] = make_float4(o[0], o[1], o[2], o[3]);
        d[1] = make_float4(o[4], o[5], o[6], o[7]);
    }
}

// ---------------------------------------------------------------------------
// t-range helper: solve L <= t*g + b <= H for t (tt = t - 127.5 domain)
__device__ __forceinline__ void rng(float g, float b, float L, float H,
                                    float& lo, float& hi) {
    if (fabsf(g) > 1e-5f) {
        float r0 = (L - b) / g, r1 = (H - b) / g;
        lo = fminf(r0, r1); hi = fmaxf(r0, r1);
    } else {
        bool in = (b >= L && b <= H);
        lo = in ? -1e9f : 1e9f;
        hi = in ? 1e9f : -1e9f;
    }
}
__device__ __forceinline__ int clampi(float v) {
    return (int)fminf(fmaxf(v, -2.f), 258.f);
}

// fully-masked edge sample (boundary t's)
__device__ __forceinline__ void sample_edge(const char* base, float ix, float iy,
                                            float* acc) {
    float xf = floorf(ix), yf = floorf(iy);
    float fx = ix - xf, fy = iy - yf;
    int x0 = (int)xf, y0 = (int)yf;
    float wx0 = 1.f - fx, wx1 = fx, wy0 = 1.f - fy, wy1 = fy;
    if ((unsigned)x0 >= NX)       wx0 = 0.f;
    if ((unsigned)(x0 + 1) >= NX) wx1 = 0.f;
    if ((unsigned)y0 >= NY)       wy0 = 0.f;
    if ((unsigned)(y0 + 1) >= NY) wy1 = 0.f;
    if ((wx0 == 0.f && wx1 == 0.f) || (wy0 == 0.f && wy1 == 0.f)) return;
    int cx0 = min(max(x0, 0), NX - 1);
    int cx1 = min(max(x0 + 1, 0), NX - 1);
    int cy0 = min(max(y0, 0), NY - 1);
    int cy1 = min(max(y0 + 1, 0), NY - 1);
    uint4 q00 = *(const uint4*)(base + ((size_t)((cy0 << 8) + cx0) << 6));
    uint4 q01 = *(const uint4*)(base + ((size_t)((cy0 << 8) + cx1) << 6));
    uint4 q10 = *(const uint4*)(base + ((size_t)((cy1 << 8) + cx0) << 6));
    uint4 q11 = *(const uint4*)(base + ((size_t)((cy1 << 8) + cx1) << 6));
    acc8h(acc, q00, wy0 * wx0);
    acc8h(acc, q01, wy0 * wx1);
    acc8h(acc, q10, wy1 * wx0);
    acc8h(acc, q11, wy1 * wx1);
}

// ---------------------------------------------------------------------------
// K2: forward projection. thread = (u, z-quarter of 8), no LDS, no atomics.
// Per-thread closed-form valid-t range; mask-free interior loop.
// grid (4 u-groups, C t-chunks, A), block 256
__global__ __launch_bounds__(256) void k_forward(const unsigned short* __restrict__ vol_h,
                                                 const float* __restrict__ trig,
                                                 float* __restrict__ part,
                                                 int tlen) {
    const int tid = threadIdx.x;
    const int a  = blockIdx.z;
    const int u  = blockIdx.x * 64 + (tid >> 2);
    const int zq = tid & 3;                 // 8 z per lane
    const int t0 = blockIdx.y * tlen;

    const float c = trig[2 * a];
    const float s = trig[2 * a + 1];
    const float uu = (float)u - 127.5f;
    const float bx = fmaf(-uu, s, 127.5f);  // ix = tt*c + bx
    const float by = fmaf(uu, c, 127.5f);   // iy = tt*s + by

    // full valid range (contribution possibly nonzero): ix,iy in [-1, 256]
    float lo1, hi1, lo2, hi2;
    rng(c, bx, -1.f, 256.f, lo1, hi1);
    rng(s, by, -1.f, 256.f, lo2, hi2);
    float fl = fmaxf(lo1, lo2), fh = fminf(hi1, hi2);
    int tF0 = max(t0, clampi(ceilf(fl + 127.5f)));
    int tF1 = min(t0 + tlen - 1, clampi(floorf(fh + 127.5f)));
    // strict interior (no clamping/masking needed): ix,iy in [1, 253.5], shrink 1
    rng(c, bx, 1.f, 253.5f, lo1, hi1);
    rng(s, by, 1.f, 253.5f, lo2, hi2);
    float il = fmaxf(lo1, lo2), ih = fminf(hi1, hi2);
    int tI0 = max(clampi(ceilf(il + 127.5f)) + 1, tF0);
    int tI1 = min(clampi(floorf(ih + 127.5f)) - 1, tF1);
    if (tI0 > tI1) { tI0 = tF1 + 1; tI1 = tF1; }

    const char* base = (const char*)vol_h + zq * 16;
    float acc[8];
    #pragma unroll
    for (int k = 0; k < 8; ++k) acc[k] = 0.f;

    for (int t = tF0; t < tI0; ++t) {
        float ttf = (float)t - 127.5f;
        sample_edge(base, fmaf(ttf, c, bx), fmaf(ttf, s, by), acc);
    }
    for (int t = tI0; t <= tI1; ++t) {
        float ttf = (float)t - 127.5f;
        float ix = fmaf(ttf, c, bx);
        float iy = fmaf(ttf, s, by);
        float xf = floorf(ix), yf = floorf(iy);
        float fx = ix - xf, fy = iy - yf;
        int row = ((int)yf << 8) + (int)xf;
        const char* p0 = base + ((size_t)row << 6);
        uint4 q00 = *(const uint4*)(p0);
        uint4 q01 = *(const uint4*)(p0 + 64);
        uint4 q10 = *(const uint4*)(p0 + 16384);
        uint4 q11 = *(const uint4*)(p0 + 16384 + 64);
        float wx0 = 1.f - fx, wy0 = 1.f - fy;
        acc8h(acc, q00, wy0 * wx0);
        acc8h(acc, q01, wy0 * fx);
        acc8h(acc, q10, fy * wx0);
        acc8h(acc, q11, fy * fx);
    }
    for (int t = tI1 + 1; t <= tF1; ++t) {
        float ttf = (float)t - 127.5f;
        sample_edge(base, fmaf(ttf, c, bx), fmaf(ttf, s, by), acc);
    }

    // unconditional store (threads with empty range write zeros — combine sums all parts)
    float4* dst = (float4*)(part + (size_t)blockIdx.y * RES_ELEMS +
                            ((a * DET0 + u) * NZ + zq * 8));
    dst[0] = make_float4(acc[0], acc[1], acc[2], acc[3]);
    dst[1] = make_float4(acc[4], acc[5], acc[6], acc[7]);
}

// ---------------------------------------------------------------------------
// K3: res_t (seeded -p_perm by K1) += sum_c part[c].  One float4 per thread,
// fully coalesced, no LDS. grid (RES_ELEMS/4/256 = 768), block 256
__global__ __launch_bounds__(256) void k_combine(const float* __restrict__ part,
                                                 float* __restrict__ res_t,
                                                 int C) {
    const int j4 = blockIdx.x * 256 + threadIdx.x;
    float4 v = ((const float4*)res_t)[j4];
    for (int c = 0; c < C; ++c) {
        float4 w = ((const float4*)(part + (size_t)c * RES_ELEMS))[j4];
        v.x += w.x; v.y += w.y; v.z += w.z; v.w += w.w;
    }
    ((float4*)res_t)[j4] = v;
}

// ---------------------------------------------------------------------------
// K4: backprojection, thread = (x, z-quarter of 4). Weights in LDS per (a,x);
// output re-transposed through LDS for coalesced stores.
// LDS 41,088 B (float2 w + int off + ob) -> 3 blocks/CU.
// The two taps are always 128 B apart; zero-weight clamped taps may read the
// trig-padding rows harmlessly (the -128B underflow stays inside ws).
// grid (NX/32, NY), block 256
__global__ __launch_bounds__(256) void k_backward(const float* __restrict__ res_t,
                                                  const float* __restrict__ trig,
                                                  float* __restrict__ out) {
    __shared__ float2 wbw[A * 32];  // 24,576 B: w0, w1
    __shared__ int    wbo[A * 32];  // 12,288 B: byte offset of tap0 (= tap1 - 128)
    __shared__ float  ob[32 * 33];  //  4,224 B output staging
    const int tid = threadIdx.x;
    const int y  = blockIdx.y;
    const int xb = blockIdx.x * 32;

    for (int e = tid; e < A * 32; e += 256) {
        int a  = e >> 5;
        int xs = e & 31;
        float cc = trig[2 * a];
        float ss = trig[2 * a + 1];
        float xx = (float)(xb + xs) - 127.5f;
        float yy = (float)y - 127.5f;
        float ub = fmaf(-xx, ss, fmaf(yy, cc, 127.5f));
        float uf = floorf(ub);
        float fu = ub - uf;
        int i0 = (int)uf;
        float w0 = ((unsigned)i0 < DET0) ? (1.f - fu) : 0.f;
        float w1 = ((unsigned)(i0 + 1) < DET0) ? fu : 0.f;
        int c1 = min(max(i0 + 1, 0), DET0);       // 0..256; tap0 row = c1-1
        wbw[e] = make_float2(w0, w1);
        wbo[e] = ((a * DET0 + c1) * NZ - NZ) << 2;
    }
    __syncthreads();

    const int xs = tid >> 3;
    const int zq = tid & 7;          // 4 z per lane
    const char* rbase = (const char*)res_t + zq * 16;
    float4 acc = make_float4(0.f, 0.f, 0.f, 0.f);
    #pragma unroll 4
    for (int a = 0; a < A; ++a) {
        float2 w  = wbw[a * 32 + xs];
        int   off = wbo[a * 32 + xs];
        float4 v0 = *(const float4*)(rbase + off);
        float4 v1 = *(const float4*)(rbase + off + 128);
        acc.x = fmaf(w.x, v0.x, fmaf(w.y, v1.x, acc.x));
        acc.y = fmaf(w.x, v0.y, fmaf(w.y, v1.y, acc.y));
        acc.z = fmaf(w.x, v0.z, fmaf(w.y, v1.z, acc.z));
        acc.w = fmaf(w.x, v0.w, fmaf(w.y, v1.w, acc.w));
    }

    ob[(zq * 4 + 0) * 33 + xs] = acc.x;
    ob[(zq * 4 + 1) * 33 + xs] = acc.y;
    ob[(zq * 4 + 2) * 33 + xs] = acc.z;
    ob[(zq * 4 + 3) * 33 + xs] = acc.w;
    __syncthreads();

    const int z  = tid >> 3;
    const int x4 = (tid & 7) * 4;
    float4 o = make_float4(ob[z * 33 + x4],     ob[z * 33 + x4 + 1],
                           ob[z * 33 + x4 + 2], ob[z * 33 + x4 + 3]);
    float4* dst = (float4*)(out + (size_t)z * (NY * NX) + y * NX + xb + x4);
    *dst = make_float4(-LAMB * o.x, -LAMB * o.y, -LAMB * o.z, -LAMB * o.w);
}

// ---------------------------------------------------------------------------
extern "C" void kernel_launch(void* const* d_in, const int* in_sizes, int n_in,
                              void* d_out, int out_size, void* d_ws, size_t ws_size,
                              hipStream_t stream) {
    const float* x = (const float*)d_in[0];   // (1,1,32,256,256)
    const float* p = (const float*)d_in[1];   // (1,1,384,8,256)
    float* out = (float*)d_out;               // (1,1,32,256,256)
    float* ws  = (float*)d_ws;

    float*          trig  = ws + TRIG_OFF;
    float*          res_t = ws + REST_OFF;
    unsigned short* vol_h = (unsigned short*)(ws + VOLB_OFF);
    float*          part  = ws + PART_OFF;

    // largest power-of-2 t-chunk count whose partials fit in ws (expect 8)
    size_t avail = ws_size / 4;
    int C = 8;
    while (C > 1 && (size_t)PART_OFF + (size_t)C * RES_ELEMS > avail) C >>= 1;
    int tlen = T / C;

    k_transpose<<<dim3(NX / 64, NY), 256, 0, stream>>>(x, vol_h, trig, p, res_t);
    k_forward  <<<dim3(4, C, A), 256, 0, stream>>>(vol_h, trig, part, tlen);
    k_combine  <<<dim3(RES_ELEMS / 4 / 256), 256, 0, stream>>>(part, res_t, C);
    k_backward <<<dim3(NX / 32, NY), 256, 0, stream>>>(res_t, trig, out);
}

// Round 4
// 193.079 us; speedup vs baseline: 1.7063x; 1.0108x over previous
//
#include <hip/hip_runtime.h>
#include <hip/hip_fp16.h>

#define A     96
#define DET0  256
#define NZ    32
#define NY    256
#define NX    256
#define T     256
#define LAMB  0.01f

// ws layout (floats):
//   trig  : [A][2]            @ 0        (192, padded to 256; padding absorbs the
//                                         harmless -128B zero-weight tap in k_backward)
//   res_t : [A][DET0][NZ]     @ 256      (786,432) fp32, seeded -p_perm by k_transpose
//   vol_h : [NY][NX][NZ] f16  @ 786,688  (2,097,152 ushorts = 1,048,576 floats)
//   part  : [C][A][DET0][NZ]  @ 1,835,264
#define TRIG_OFF  0
#define REST_OFF  256
#define VOLB_OFF  786688
#define PART_OFF  1835264
#define RES_ELEMS 786432

// accumulate 2 f16 (packed in a dword) * w into acc[0..1] — fpext+fma is the
// canonical pattern for v_fma_mix_f32 (f32 fma reading f16 src half), no unpack.
__device__ __forceinline__ void accp(float* acc, unsigned v, float w) {
    __half2 h = *reinterpret_cast<__half2*>(&v);
    acc[0] = fmaf(w, __low2float(h),  acc[0]);
    acc[1] = fmaf(w, __high2float(h), acc[1]);
}
__device__ __forceinline__ void acc8h(float* acc, uint4 q, float w) {
    accp(acc + 0, q.x, w);
    accp(acc + 2, q.y, w);
    accp(acc + 4, q.z, w);
    accp(acc + 6, q.w, w);
}

// ---------------------------------------------------------------------------
// K1: transpose vol (z,y,x) fp32 -> vol_h (y,x,z) f16; fill trig table;
//     seed res_t = -p_perm (blocks with y < A double as (u-chunk, angle) seeders).
// grid (NX/64, NY), block 256
__global__ __launch_bounds__(256) void k_transpose(const float* __restrict__ src,
                                                   unsigned short* __restrict__ vol_h,
                                                   float* __restrict__ trig,
                                                   const float* __restrict__ p,
                                                   float* __restrict__ res_t) {
    __shared__ float lds[64 * 33];   // 2112 floats; seed phase reuses 32x65 <= 2078
    const int y   = blockIdx.y;
    const int x0  = blockIdx.x * 64;
    const int tid = threadIdx.x;

    if (blockIdx.x == 0 && y == 0 && tid < A) {
        float th = (float)tid * (float)(3.14159265358979323846 / (double)A);
        trig[2 * tid]     = cosf(th);
        trig[2 * tid + 1] = sinf(th);
    }

    const int xr = tid & 63;
    const int zr = tid >> 6;  // 0..3
    #pragma unroll
    for (int pz = 0; pz < 8; ++pz) {
        int z = pz * 4 + zr;
        lds[xr * 33 + z] = src[(z * NY + y) * NX + x0 + xr];
    }
    __syncthreads();
    const int zw = tid & 31;
    const int xw = tid >> 5;  // 0..7
    #pragma unroll
    for (int px = 0; px < 8; ++px) {
        int xi = px * 8 + xw;
        vol_h[(y * NX + x0 + xi) * NZ + zw] =
            __half_as_ushort(__float2half(lds[xi * 33 + zw]));
    }

    // ---- seed res_t[a][u][z] = -p[a][perm(z)][u] for a = y, u-chunk = blockIdx.x
    if (y < A) {
        const int a  = y;
        const int u0 = blockIdx.x * 64;
        __syncthreads();                      // transpose reads of lds are done
        const int col = tid & 63;
        const int r0  = tid >> 6;
        #pragma unroll
        for (int i = 0; i < 8; ++i) {
            int r = i * 4 + r0;
            lds[r * 65 + col] = p[a * 8192 + r * 256 + u0 + col];
        }
        __syncthreads();
        const int ul = tid >> 2;
        const int zb = (tid & 3) * 8;
        float o[8];
        #pragma unroll
        for (int k = 0; k < 8; ++k) {
            int z = zb + k;
            int r = ((z & 7) << 2) + (z >> 3);
            o[k] = -lds[r * 65 + ul];
        }
        float4* d = (float4*)(res_t + (a * DET0 + u0 + ul) * NZ + zb);
        d[0] = make_float4(o[0], o[1], o[2], o[3]);
        d[1] = make_float4(o[4], o[5], o[6], o[7]);
    }
}

// ---------------------------------------------------------------------------
// t-range helper: solve L <= t*g + b <= H for t (tt = t - 127.5 domain)
__device__ __forceinline__ void rng(float g, float b, float L, float H,
                                    float& lo, float& hi) {
    if (fabsf(g) > 1e-5f) {
        float r0 = (L - b) / g, r1 = (H - b) / g;
        lo = fminf(r0, r1); hi = fmaxf(r0, r1);
    } else {
        bool in = (b >= L && b <= H);
        lo = in ? -1e9f : 1e9f;
        hi = in ? 1e9f : -1e9f;
    }
}
__device__ __forceinline__ int clampi(float v) {
    return (int)fminf(fmaxf(v, -2.f), 258.f);
}

// fully-masked edge sample (boundary t's)
__device__ __forceinline__ void sample_edge(const char* base, float ix, float iy,
                                            float* acc) {
    float xf = floorf(ix), yf = floorf(iy);
    float fx = ix - xf, fy = iy - yf;
    int x0 = (int)xf, y0 = (int)yf;
    float wx0 = 1.f - fx, wx1 = fx, wy0 = 1.f - fy, wy1 = fy;
    if ((unsigned)x0 >= NX)       wx0 = 0.f;
    if ((unsigned)(x0 + 1) >= NX) wx1 = 0.f;
    if ((unsigned)y0 >= NY)       wy0 = 0.f;
    if ((unsigned)(y0 + 1) >= NY) wy1 = 0.f;
    if ((wx0 == 0.f && wx1 == 0.f) || (wy0 == 0.f && wy1 == 0.f)) return;
    int cx0 = min(max(x0, 0), NX - 1);
    int cx1 = min(max(x0 + 1, 0), NX - 1);
    int cy0 = min(max(y0, 0), NY - 1);
    int cy1 = min(max(y0 + 1, 0), NY - 1);
    uint4 q00 = *(const uint4*)(base + ((size_t)((cy0 << 8) + cx0) << 6));
    uint4 q01 = *(const uint4*)(base + ((size_t)((cy0 << 8) + cx1) << 6));
    uint4 q10 = *(const uint4*)(base + ((size_t)((cy1 << 8) + cx0) << 6));
    uint4 q11 = *(const uint4*)(base + ((size_t)((cy1 << 8) + cx1) << 6));
    acc8h(acc, q00, wy0 * wx0);
    acc8h(acc, q01, wy0 * wx1);
    acc8h(acc, q10, wy1 * wx0);
    acc8h(acc, q11, wy1 * wx1);
}

// ---------------------------------------------------------------------------
// K2: forward projection. thread = (u, z-quarter of 8), no LDS, no atomics.
// Per-ray load balance: each thread computes its FULL valid t-range [F0,F1],
// then handles the blockIdx.y-th of C equal slices of ITS OWN range. All
// blocks carry statistically identical work (kills the 40%-occupancy tail).
// grid (4 u-groups, C ray-slices, A), block 256
__global__ __launch_bounds__(256) void k_forward(const unsigned short* __restrict__ vol_h,
                                                 const float* __restrict__ trig,
                                                 float* __restrict__ part) {
    const int tid = threadIdx.x;
    const int a   = blockIdx.z;
    const int u   = blockIdx.x * 64 + (tid >> 2);
    const int zq  = tid & 3;                // 8 z per lane
    const int cid = blockIdx.y;
    const int C   = gridDim.y;

    const float c = trig[2 * a];
    const float s = trig[2 * a + 1];
    const float uu = (float)u - 127.5f;
    const float bx = fmaf(-uu, s, 127.5f);  // ix = tt*c + bx
    const float by = fmaf(uu, c, 127.5f);   // iy = tt*s + by

    // full valid range (contribution possibly nonzero): ix,iy in [-1, 256]
    float lo1, hi1, lo2, hi2;
    rng(c, bx, -1.f, 256.f, lo1, hi1);
    rng(s, by, -1.f, 256.f, lo2, hi2);
    float fl = fmaxf(lo1, lo2), fh = fminf(hi1, hi2);
    int F0 = max(0,     clampi(ceilf(fl + 127.5f)));
    int F1 = min(T - 1, clampi(floorf(fh + 127.5f)));
    int len = F1 - F0 + 1; if (len < 0) len = 0;
    // this block's slice of THIS ray's range (disjoint, union = [F0,F1])
    int b0 = F0 + (len * cid) / C;
    int b1 = F0 + (len * (cid + 1)) / C - 1;
    // strict interior (no clamping/masking needed): ix,iy in [1, 253.5], shrink 1
    rng(c, bx, 1.f, 253.5f, lo1, hi1);
    rng(s, by, 1.f, 253.5f, lo2, hi2);
    float il = fmaxf(lo1, lo2), ih = fminf(hi1, hi2);
    int tI0 = max(clampi(ceilf(il + 127.5f)) + 1, b0);
    int tI1 = min(clampi(floorf(ih + 127.5f)) - 1, b1);
    if (tI0 > tI1) { tI0 = b1 + 1; tI1 = b1; }

    const char* base = (const char*)vol_h + zq * 16;
    float acc[8];
    #pragma unroll
    for (int k = 0; k < 8; ++k) acc[k] = 0.f;

    for (int t = b0; t < tI0; ++t) {
        float ttf = (float)t - 127.5f;
        sample_edge(base, fmaf(ttf, c, bx), fmaf(ttf, s, by), acc);
    }
    for (int t = tI0; t <= tI1; ++t) {
        float ttf = (float)t - 127.5f;
        float ix = fmaf(ttf, c, bx);
        float iy = fmaf(ttf, s, by);
        float xf = floorf(ix), yf = floorf(iy);
        float fx = ix - xf, fy = iy - yf;
        int row = ((int)yf << 8) + (int)xf;
        const char* p0 = base + ((size_t)row << 6);
        uint4 q00 = *(const uint4*)(p0);
        uint4 q01 = *(const uint4*)(p0 + 64);
        uint4 q10 = *(const uint4*)(p0 + 16384);
        uint4 q11 = *(const uint4*)(p0 + 16384 + 64);
        float wx0 = 1.f - fx, wy0 = 1.f - fy;
        acc8h(acc, q00, wy0 * wx0);
        acc8h(acc, q01, wy0 * fx);
        acc8h(acc, q10, fy * wx0);
        acc8h(acc, q11, fy * fx);
    }
    for (int t = tI1 + 1; t <= b1; ++t) {
        float ttf = (float)t - 127.5f;
        sample_edge(base, fmaf(ttf, c, bx), fmaf(ttf, s, by), acc);
    }

    // unconditional store (threads with empty slice write zeros — combine sums all parts)
    float4* dst = (float4*)(part + (size_t)cid * RES_ELEMS +
                            ((a * DET0 + u) * NZ + zq * 8));
    dst[0] = make_float4(acc[0], acc[1], acc[2], acc[3]);
    dst[1] = make_float4(acc[4], acc[5], acc[6], acc[7]);
}

// ---------------------------------------------------------------------------
// K3: res_t (seeded -p_perm by K1) += sum_c part[c].  One float4 per thread,
// fully coalesced, no LDS. grid (RES_ELEMS/4/256 = 768), block 256
__global__ __launch_bounds__(256) void k_combine(const float* __restrict__ part,
                                                 float* __restrict__ res_t,
                                                 int C) {
    const int j4 = blockIdx.x * 256 + threadIdx.x;
    float4 v = ((const float4*)res_t)[j4];
    for (int c = 0; c < C; ++c) {
        float4 w = ((const float4*)(part + (size_t)c * RES_ELEMS))[j4];
        v.x += w.x; v.y += w.y; v.z += w.z; v.w += w.w;
    }
    ((float4*)res_t)[j4] = v;
}

// ---------------------------------------------------------------------------
// K4: backprojection, thread = (x, z-quarter of 4). Weights in LDS per (a,x);
// output re-transposed through LDS for coalesced stores.
// LDS 41,088 B (float2 w + int off + ob) -> 3 blocks/CU.
// The two taps are always 128 B apart; zero-weight clamped taps may read the
// trig-padding rows harmlessly (the -128B underflow stays inside ws).
// grid (NX/32, NY), block 256
__global__ __launch_bounds__(256) void k_backward(const float* __restrict__ res_t,
                                                  const float* __restrict__ trig,
                                                  float* __restrict__ out) {
    __shared__ float2 wbw[A * 32];  // 24,576 B: w0, w1
    __shared__ int    wbo[A * 32];  // 12,288 B: byte offset of tap0 (= tap1 - 128)
    __shared__ float  ob[32 * 33];  //  4,224 B output staging
    const int tid = threadIdx.x;
    const int y  = blockIdx.y;
    const int xb = blockIdx.x * 32;

    for (int e = tid; e < A * 32; e += 256) {
        int a  = e >> 5;
        int xs = e & 31;
        float cc = trig[2 * a];
        float ss = trig[2 * a + 1];
        float xx = (float)(xb + xs) - 127.5f;
        float yy = (float)y - 127.5f;
        float ub = fmaf(-xx, ss, fmaf(yy, cc, 127.5f));
        float uf = floorf(ub);
        float fu = ub - uf;
        int i0 = (int)uf;
        float w0 = ((unsigned)i0 < DET0) ? (1.f - fu) : 0.f;
        float w1 = ((unsigned)(i0 + 1) < DET0) ? fu : 0.f;
        int c1 = min(max(i0 + 1, 0), DET0);       // 0..256; tap0 row = c1-1
        wbw[e] = make_float2(w0, w1);
        wbo[e] = ((a * DET0 + c1) * NZ - NZ) << 2;
    }
    __syncthreads();

    const int xs = tid >> 3;
    const int zq = tid & 7;          // 4 z per lane
    const char* rbase = (const char*)res_t + zq * 16;
    float4 acc = make_float4(0.f, 0.f, 0.f, 0.f);
    #pragma unroll 4
    for (int a = 0; a < A; ++a) {
        float2 w  = wbw[a * 32 + xs];
        int   off = wbo[a * 32 + xs];
        float4 v0 = *(const float4*)(rbase + off);
        float4 v1 = *(const float4*)(rbase + off + 128);
        acc.x = fmaf(w.x, v0.x, fmaf(w.y, v1.x, acc.x));
        acc.y = fmaf(w.x, v0.y, fmaf(w.y, v1.y, acc.y));
        acc.z = fmaf(w.x, v0.z, fmaf(w.y, v1.z, acc.z));
        acc.w = fmaf(w.x, v0.w, fmaf(w.y, v1.w, acc.w));
    }

    ob[(zq * 4 + 0) * 33 + xs] = acc.x;
    ob[(zq * 4 + 1) * 33 + xs] = acc.y;
    ob[(zq * 4 + 2) * 33 + xs] = acc.z;
    ob[(zq * 4 + 3) * 33 + xs] = acc.w;
    __syncthreads();

    const int z  = tid >> 3;
    const int x4 = (tid & 7) * 4;
    float4 o = make_float4(ob[z * 33 + x4],     ob[z * 33 + x4 + 1],
                           ob[z * 33 + x4 + 2], ob[z * 33 + x4 + 3]);
    float4* dst = (float4*)(out + (size_t)z * (NY * NX) + y * NX + xb + x4);
    *dst = make_float4(-LAMB * o.x, -LAMB * o.y, -LAMB * o.z, -LAMB * o.w);
}

// ---------------------------------------------------------------------------
extern "C" void kernel_launch(void* const* d_in, const int* in_sizes, int n_in,
                              void* d_out, int out_size, void* d_ws, size_t ws_size,
                              hipStream_t stream) {
    const float* x = (const float*)d_in[0];   // (1,1,32,256,256)
    const float* p = (const float*)d_in[1];   // (1,1,384,8,256)
    float* out = (float*)d_out;               // (1,1,32,256,256)
    float* ws  = (float*)d_ws;

    float*          trig  = ws + TRIG_OFF;
    float*          res_t = ws + REST_OFF;
    unsigned short* vol_h = (unsigned short*)(ws + VOLB_OFF);
    float*          part  = ws + PART_OFF;

    // largest power-of-2 slice count whose partials fit in ws (expect 8)
    size_t avail = ws_size / 4;
    int C = 8;
    while (C > 1 && (size_t)PART_OFF + (size_t)C * RES_ELEMS > avail) C >>= 1;

    k_transpose<<<dim3(NX / 64, NY), 256, 0, stream>>>(x, vol_h, trig, p, res_t);
    k_forward  <<<dim3(4, C, A), 256, 0, stream>>>(vol_h, trig, part);
    k_combine  <<<dim3(RES_ELEMS / 4 / 256), 256, 0, stream>>>(part, res_t, C);
    k_backward <<<dim3(NX / 32, NY), 256, 0, stream>>>(res_t, trig, out);
}

// Round 5
// 192.795 us; speedup vs baseline: 1.7088x; 1.0015x over previous
//
#include <hip/hip_runtime.h>
#include <hip/hip_fp16.h>

#define A     96
#define DET0  256
#define NZ    32
#define NY    256
#define NX    256
#define T     256
#define LAMB  0.01f

// ws layout (floats):
//   trig  : [A][2]            @ 0        (192, padded to 256; padding absorbs the
//                                         harmless -128B zero-weight tap in k_backward)
//   res_t : [A][DET0][NZ]     @ 256      (786,432) fp32, seeded -p_perm by k_transpose
//   vol_h : [NY][NX][NZ] f16  @ 786,688  (2,097,152 ushorts = 1,048,576 floats)
//   part  : [C][A][DET0][NZ]  @ 1,835,264
// NOTE: k_forward's 1-deep lookahead may compute addresses up to ~33 KB outside
// vol_h; those land in res_t/part regions (still inside ws) and are never consumed.
#define TRIG_OFF  0
#define REST_OFF  256
#define VOLB_OFF  786688
#define PART_OFF  1835264
#define RES_ELEMS 786432

// accumulate 2 f16 (packed in a dword) * w into acc[0..1] — fpext+fma is the
// canonical pattern for v_fma_mix_f32 (f32 fma reading f16 src half), no unpack.
__device__ __forceinline__ void accp(float* acc, unsigned v, float w) {
    __half2 h = *reinterpret_cast<__half2*>(&v);
    acc[0] = fmaf(w, __low2float(h),  acc[0]);
    acc[1] = fmaf(w, __high2float(h), acc[1]);
}
__device__ __forceinline__ void acc8h(float* acc, uint4 q, float w) {
    accp(acc + 0, q.x, w);
    accp(acc + 2, q.y, w);
    accp(acc + 4, q.z, w);
    accp(acc + 6, q.w, w);
}

// ---------------------------------------------------------------------------
// K1: transpose vol (z,y,x) fp32 -> vol_h (y,x,z) f16; fill trig table;
//     seed res_t = -p_perm (blocks with y < A double as (u-chunk, angle) seeders).
// grid (NX/64, NY), block 256
__global__ __launch_bounds__(256) void k_transpose(const float* __restrict__ src,
                                                   unsigned short* __restrict__ vol_h,
                                                   float* __restrict__ trig,
                                                   const float* __restrict__ p,
                                                   float* __restrict__ res_t) {
    __shared__ float lds[64 * 33];   // 2112 floats; seed phase reuses 32x65 <= 2078
    const int y   = blockIdx.y;
    const int x0  = blockIdx.x * 64;
    const int tid = threadIdx.x;

    if (blockIdx.x == 0 && y == 0 && tid < A) {
        float th = (float)tid * (float)(3.14159265358979323846 / (double)A);
        trig[2 * tid]     = cosf(th);
        trig[2 * tid + 1] = sinf(th);
    }

    const int xr = tid & 63;
    const int zr = tid >> 6;  // 0..3
    #pragma unroll
    for (int pz = 0; pz < 8; ++pz) {
        int z = pz * 4 + zr;
        lds[xr * 33 + z] = src[(z * NY + y) * NX + x0 + xr];
    }
    __syncthreads();
    const int zw = tid & 31;
    const int xw = tid >> 5;  // 0..7
    #pragma unroll
    for (int px = 0; px < 8; ++px) {
        int xi = px * 8 + xw;
        vol_h[(y * NX + x0 + xi) * NZ + zw] =
            __half_as_ushort(__float2half(lds[xi * 33 + zw]));
    }

    // ---- seed res_t[a][u][z] = -p[a][perm(z)][u] for a = y, u-chunk = blockIdx.x
    if (y < A) {
        const int a  = y;
        const int u0 = blockIdx.x * 64;
        __syncthreads();                      // transpose reads of lds are done
        const int col = tid & 63;
        const int r0  = tid >> 6;
        #pragma unroll
        for (int i = 0; i < 8; ++i) {
            int r = i * 4 + r0;
            lds[r * 65 + col] = p[a * 8192 + r * 256 + u0 + col];
        }
        __syncthreads();
        const int ul = tid >> 2;
        const int zb = (tid & 3) * 8;
        float o[8];
        #pragma unroll
        for (int k = 0; k < 8; ++k) {
            int z = zb + k;
            int r = ((z & 7) << 2) + (z >> 3);
            o[k] = -lds[r * 65 + ul];
        }
        float4* d = (float4*)(res_t + (a * DET0 + u0 + ul) * NZ + zb);
        d[0] = make_float4(o[0], o[1], o[2], o[3]);
        d[1] = make_float4(o[4], o[5], o[6], o[7]);
    }
}

// ---------------------------------------------------------------------------
// t-range helper: solve L <= t*g + b <= H for t (tt = t - 127.5 domain)
__device__ __forceinline__ void rng(float g, float b, float L, float H,
                                    float& lo, float& hi) {
    if (fabsf(g) > 1e-5f) {
        float r0 = (L - b) / g, r1 = (H - b) / g;
        lo = fminf(r0, r1); hi = fmaxf(r0, r1);
    } else {
        bool in = (b >= L && b <= H);
        lo = in ? -1e9f : 1e9f;
        hi = in ? 1e9f : -1e9f;
    }
}
__device__ __forceinline__ int clampi(float v) {
    return (int)fminf(fmaxf(v, -2.f), 258.f);
}

// fully-masked edge sample (boundary t's)
__device__ __forceinline__ void sample_edge(const char* base, float ix, float iy,
                                            float* acc) {
    float xf = floorf(ix), yf = floorf(iy);
    float fx = ix - xf, fy = iy - yf;
    int x0 = (int)xf, y0 = (int)yf;
    float wx0 = 1.f - fx, wx1 = fx, wy0 = 1.f - fy, wy1 = fy;
    if ((unsigned)x0 >= NX)       wx0 = 0.f;
    if ((unsigned)(x0 + 1) >= NX) wx1 = 0.f;
    if ((unsigned)y0 >= NY)       wy0 = 0.f;
    if ((unsigned)(y0 + 1) >= NY) wy1 = 0.f;
    if ((wx0 == 0.f && wx1 == 0.f) || (wy0 == 0.f && wy1 == 0.f)) return;
    int cx0 = min(max(x0, 0), NX - 1);
    int cx1 = min(max(x0 + 1, 0), NX - 1);
    int cy0 = min(max(y0, 0), NY - 1);
    int cy1 = min(max(y0 + 1, 0), NY - 1);
    uint4 q00 = *(const uint4*)(base + ((size_t)((cy0 << 8) + cx0) << 6));
    uint4 q01 = *(const uint4*)(base + ((size_t)((cy0 << 8) + cx1) << 6));
    uint4 q10 = *(const uint4*)(base + ((size_t)((cy1 << 8) + cx0) << 6));
    uint4 q11 = *(const uint4*)(base + ((size_t)((cy1 << 8) + cx1) << 6));
    acc8h(acc, q00, wy0 * wx0);
    acc8h(acc, q01, wy0 * wx1);
    acc8h(acc, q10, wy1 * wx0);
    acc8h(acc, q11, wy1 * wx1);
}

// ---------------------------------------------------------------------------
// K2: forward projection. thread = (u, z-quarter of 8), no LDS, no atomics.
// Per-ray slicing (round 4) + 1-deep software pipeline: loads for t+1 issued
// before t's FMAs consume their loads -> 8 loads in flight, latency hidden.
// grid (4 u-groups, C ray-slices, A), block 256
__global__ __launch_bounds__(256) void k_forward(const unsigned short* __restrict__ vol_h,
                                                 const float* __restrict__ trig,
                                                 float* __restrict__ part) {
    const int tid = threadIdx.x;
    const int a   = blockIdx.z;
    const int u   = blockIdx.x * 64 + (tid >> 2);
    const int zq  = tid & 3;                // 8 z per lane
    const int cid = blockIdx.y;
    const int C   = gridDim.y;

    const float c = trig[2 * a];
    const float s = trig[2 * a + 1];
    const float uu = (float)u - 127.5f;
    const float bx = fmaf(-uu, s, 127.5f);  // ix = tt*c + bx
    const float by = fmaf(uu, c, 127.5f);   // iy = tt*s + by

    // full valid range (contribution possibly nonzero): ix,iy in [-1, 256]
    float lo1, hi1, lo2, hi2;
    rng(c, bx, -1.f, 256.f, lo1, hi1);
    rng(s, by, -1.f, 256.f, lo2, hi2);
    float fl = fmaxf(lo1, lo2), fh = fminf(hi1, hi2);
    int F0 = max(0,     clampi(ceilf(fl + 127.5f)));
    int F1 = min(T - 1, clampi(floorf(fh + 127.5f)));
    int len = F1 - F0 + 1; if (len < 0) len = 0;
    // this block's slice of THIS ray's range (disjoint, union = [F0,F1])
    int b0 = F0 + (len * cid) / C;
    int b1 = F0 + (len * (cid + 1)) / C - 1;
    // strict interior (no clamping/masking needed): ix,iy in [1, 253.5], shrink 1
    rng(c, bx, 1.f, 253.5f, lo1, hi1);
    rng(s, by, 1.f, 253.5f, lo2, hi2);
    float il = fmaxf(lo1, lo2), ih = fminf(hi1, hi2);
    int tI0 = max(clampi(ceilf(il + 127.5f)) + 1, b0);
    int tI1 = min(clampi(floorf(ih + 127.5f)) - 1, b1);
    if (tI0 > tI1) { tI0 = b1 + 1; tI1 = b1; }

    const char* base = (const char*)vol_h + zq * 16;
    float acc[8];
    #pragma unroll
    for (int k = 0; k < 8; ++k) acc[k] = 0.f;

    for (int t = b0; t < tI0; ++t) {
        float ttf = (float)t - 127.5f;
        sample_edge(base, fmaf(ttf, c, bx), fmaf(ttf, s, by), acc);
    }

    if (tI0 <= tI1) {
        // ---- pipelined interior: current regs (c**, fxc, fyc) preloaded
        float ttf = (float)tI0 - 127.5f;
        float ix = fmaf(ttf, c, bx);
        float iy = fmaf(ttf, s, by);
        float xf = floorf(ix), yf = floorf(iy);
        float fxc = ix - xf, fyc = iy - yf;
        const char* p0 = base + ((size_t)(((int)yf << 8) + (int)xf) << 6);
        uint4 c00 = *(const uint4*)(p0);
        uint4 c01 = *(const uint4*)(p0 + 64);
        uint4 c10 = *(const uint4*)(p0 + 16384);
        uint4 c11 = *(const uint4*)(p0 + 16384 + 64);
        for (int t = tI0; t <= tI1; ++t) {
            // issue next iteration's loads (t+1 == tI1+1 loads garbage inside ws,
            // never consumed)
            float ttn = (float)(t + 1) - 127.5f;
            float ixn = fmaf(ttn, c, bx);
            float iyn = fmaf(ttn, s, by);
            float xfn = floorf(ixn), yfn = floorf(iyn);
            float fxn = ixn - xfn, fyn = iyn - yfn;
            const char* pn = base + ((size_t)(((int)yfn << 8) + (int)xfn) << 6);
            uint4 n00 = *(const uint4*)(pn);
            uint4 n01 = *(const uint4*)(pn + 64);
            uint4 n10 = *(const uint4*)(pn + 16384);
            uint4 n11 = *(const uint4*)(pn + 16384 + 64);
            // consume current
            float wx0 = 1.f - fxc, wy0 = 1.f - fyc;
            acc8h(acc, c00, wy0 * wx0);
            acc8h(acc, c01, wy0 * fxc);
            acc8h(acc, c10, fyc * wx0);
            acc8h(acc, c11, fyc * fxc);
            // rotate
            c00 = n00; c01 = n01; c10 = n10; c11 = n11;
            fxc = fxn; fyc = fyn;
        }
    }

    for (int t = tI1 + 1; t <= b1; ++t) {
        float ttf = (float)t - 127.5f;
        sample_edge(base, fmaf(ttf, c, bx), fmaf(ttf, s, by), acc);
    }

    // unconditional store (threads with empty slice write zeros — combine sums all parts)
    float4* dst = (float4*)(part + (size_t)cid * RES_ELEMS +
                            ((a * DET0 + u) * NZ + zq * 8));
    dst[0] = make_float4(acc[0], acc[1], acc[2], acc[3]);
    dst[1] = make_float4(acc[4], acc[5], acc[6], acc[7]);
}

// ---------------------------------------------------------------------------
// K3: res_t (seeded -p_perm by K1) += sum_c part[c].  One float4 per thread,
// fully coalesced, no LDS. grid (RES_ELEMS/4/256 = 768), block 256
__global__ __launch_bounds__(256) void k_combine(const float* __restrict__ part,
                                                 float* __restrict__ res_t,
                                                 int C) {
    const int j4 = blockIdx.x * 256 + threadIdx.x;
    float4 v = ((const float4*)res_t)[j4];
    for (int c = 0; c < C; ++c) {
        float4 w = ((const float4*)(part + (size_t)c * RES_ELEMS))[j4];
        v.x += w.x; v.y += w.y; v.z += w.z; v.w += w.w;
    }
    ((float4*)res_t)[j4] = v;
}

// ---------------------------------------------------------------------------
// K4: backprojection, thread = (x, z-quarter of 4). Weights in LDS per (a,x);
// output re-transposed through LDS for coalesced stores.
// LDS 41,088 B (float2 w + int off + ob) -> 3 blocks/CU.
// The two taps are always 128 B apart; zero-weight clamped taps may read the
// trig-padding rows harmlessly (the -128B underflow stays inside ws).
// grid (NX/32, NY), block 256
__global__ __launch_bounds__(256) void k_backward(const float* __restrict__ res_t,
                                                  const float* __restrict__ trig,
                                                  float* __restrict__ out) {
    __shared__ float2 wbw[A * 32];  // 24,576 B: w0, w1
    __shared__ int    wbo[A * 32];  // 12,288 B: byte offset of tap0 (= tap1 - 128)
    __shared__ float  ob[32 * 33];  //  4,224 B output staging
    const int tid = threadIdx.x;
    const int y  = blockIdx.y;
    const int xb = blockIdx.x * 32;

    for (int e = tid; e < A * 32; e += 256) {
        int a  = e >> 5;
        int xs = e & 31;
        float cc = trig[2 * a];
        float ss = trig[2 * a + 1];
        float xx = (float)(xb + xs) - 127.5f;
        float yy = (float)y - 127.5f;
        float ub = fmaf(-xx, ss, fmaf(yy, cc, 127.5f));
        float uf = floorf(ub);
        float fu = ub - uf;
        int i0 = (int)uf;
        float w0 = ((unsigned)i0 < DET0) ? (1.f - fu) : 0.f;
        float w1 = ((unsigned)(i0 + 1) < DET0) ? fu : 0.f;
        int c1 = min(max(i0 + 1, 0), DET0);       // 0..256; tap0 row = c1-1
        wbw[e] = make_float2(w0, w1);
        wbo[e] = ((a * DET0 + c1) * NZ - NZ) << 2;
    }
    __syncthreads();

    const int xs = tid >> 3;
    const int zq = tid & 7;          // 4 z per lane
    const char* rbase = (const char*)res_t + zq * 16;
    float4 acc = make_float4(0.f, 0.f, 0.f, 0.f);
    #pragma unroll 4
    for (int a = 0; a < A; ++a) {
        float2 w  = wbw[a * 32 + xs];
        int   off = wbo[a * 32 + xs];
        float4 v0 = *(const float4*)(rbase + off);
        float4 v1 = *(const float4*)(rbase + off + 128);
        acc.x = fmaf(w.x, v0.x, fmaf(w.y, v1.x, acc.x));
        acc.y = fmaf(w.x, v0.y, fmaf(w.y, v1.y, acc.y));
        acc.z = fmaf(w.x, v0.z, fmaf(w.y, v1.z, acc.z));
        acc.w = fmaf(w.x, v0.w, fmaf(w.y, v1.w, acc.w));
    }

    ob[(zq * 4 + 0) * 33 + xs] = acc.x;
    ob[(zq * 4 + 1) * 33 + xs] = acc.y;
    ob[(zq * 4 + 2) * 33 + xs] = acc.z;
    ob[(zq * 4 + 3) * 33 + xs] = acc.w;
    __syncthreads();

    const int z  = tid >> 3;
    const int x4 = (tid & 7) * 4;
    float4 o = make_float4(ob[z * 33 + x4],     ob[z * 33 + x4 + 1],
                           ob[z * 33 + x4 + 2], ob[z * 33 + x4 + 3]);
    float4* dst = (float4*)(out + (size_t)z * (NY * NX) + y * NX + xb + x4);
    *dst = make_float4(-LAMB * o.x, -LAMB * o.y, -LAMB * o.z, -LAMB * o.w);
}

// ---------------------------------------------------------------------------
extern "C" void kernel_launch(void* const* d_in, const int* in_sizes, int n_in,
                              void* d_out, int out_size, void* d_ws, size_t ws_size,
                              hipStream_t stream) {
    const float* x = (const float*)d_in[0];   // (1,1,32,256,256)
    const float* p = (const float*)d_in[1];   // (1,1,384,8,256)
    float* out = (float*)d_out;               // (1,1,32,256,256)
    float* ws  = (float*)d_ws;

    float*          trig  = ws + TRIG_OFF;
    float*          res_t = ws + REST_OFF;
    unsigned short* vol_h = (unsigned short*)(ws + VOLB_OFF);
    float*          part  = ws + PART_OFF;

    // largest power-of-2 slice count whose partials fit in ws (expect 8)
    size_t avail = ws_size / 4;
    int C = 8;
    while (C > 1 && (size_t)PART_OFF + (size_t)C * RES_ELEMS > avail) C >>= 1;

    k_transpose<<<dim3(NX / 64, NY), 256, 0, stream>>>(x, vol_h, trig, p, res_t);
    k_forward  <<<dim3(4, C, A), 256, 0, stream>>>(vol_h, trig, part);
    k_combine  <<<dim3(RES_ELEMS / 4 / 256), 256, 0, stream>>>(part, res_t, C);
    k_backward <<<dim3(NX / 32, NY), 256, 0, stream>>>(res_t, trig, out);
}